// Round 17
// baseline (126.275 us; speedup 1.0000x reference)
//
#include <hip/hip_runtime.h>
#include <math.h>

// B=2, H=16, S=2048, DK=64
#define S_LEN 2048
#define NCH   32          // S/64 chunks
#define N_BH  32

typedef short bf16x8 __attribute__((ext_vector_type(8)));
typedef _Float16 f16x8 __attribute__((ext_vector_type(8)));
typedef float f32x4  __attribute__((ext_vector_type(4)));
typedef unsigned short u16;
typedef unsigned short u16x8 __attribute__((ext_vector_type(8)));
typedef unsigned long long u64;

#define MFMA32(a,b,c) __builtin_amdgcn_mfma_f32_16x16x32_bf16((a),(b),(c),0,0,0)
#define MFMAH(a,b,c)  __builtin_amdgcn_mfma_f32_16x16x32_f16((a),(b),(c),0,0,0)
#define EXP2(x) __builtin_amdgcn_exp2f(x)

// (1/sqrt(64)) * log2(e): scores in log2 units; exp2 = one v_exp_f32.
#define SC        0.18033688011112042f
// masked P value = exp2(-14) EXACTLY (power of two, exact in f32 and f16).
// Fully-masked column degrades to EXACT uniform 1/2048.
#define MASKED_P  6.103515625e-05f

__device__ __forceinline__ u16 f2h(float x) {
  union { _Float16 h; u16 u; } v;
  v.h = (_Float16)x;          // RNE
  return v.u;
}
__device__ __forceinline__ u16 f2bf_rne(float x) {
  unsigned u = __float_as_uint(x);
  return (u16)((u + 0x7FFF + ((u >> 16) & 1)) >> 16);
}
__device__ __forceinline__ void bfsplit(float x, u16& h, u16& l) {
  unsigned u = __float_as_uint(x);
  h = (u16)(u >> 16);
  float hf = __uint_as_float(u & 0xFFFF0000u);
  l = f2bf_rne(x - hf);
}

// ---------------------------------------------------------------------------
// pack_mask (fallback path only).
// ---------------------------------------------------------------------------
__global__ __launch_bounds__(256) void pack_mask(
    const int* __restrict__ mask, u64* __restrict__ bits) {
  const int word = blockIdx.x * 4 + (threadIdx.x >> 6);
  const int lane = threadIdx.x & 63;
  const int row = word >> 5, wc = word & 31;
  int m = mask[(size_t)row * S_LEN + wc * 64 + lane];
  u64 b = __ballot(m != 0);
  if (lane == 0) bits[word] = b;
}

// ---------------------------------------------------------------------------
// prep_qk_mask: blocks <1024 convert Q*SC / K -> fp16 swizzled planes
// plane[row*64 + (col ^ ((row&7)*8))]; blocks >=1024 bit-pack the mask.
// ---------------------------------------------------------------------------
__global__ __launch_bounds__(256) void prep_qk_mask(
    const float* __restrict__ Q, const float* __restrict__ K,
    const int* __restrict__ mask,
    u16* __restrict__ qf, u16* __restrict__ kf, u64* __restrict__ bits) {
  const int b = blockIdx.x;
  const int tid = threadIdx.x;
  if (b < 1024) {
    const int slot = tid & 15, r0 = tid >> 4;
    const size_t rowbase = (size_t)b * 64;
#pragma unroll
    for (int p = 0; p < 4; ++p) {
      const size_t row = rowbase + p * 16 + r0;
      const size_t dst = row * 64 + ((slot * 4) ^ (((int)row & 7) << 3));
      float4 xq = *(const float4*)(Q + row * 64 + slot * 4);
      *(ushort4*)(qf + dst) = make_ushort4(
          f2h(xq.x * SC), f2h(xq.y * SC), f2h(xq.z * SC), f2h(xq.w * SC));
      float4 xk = *(const float4*)(K + row * 64 + slot * 4);
      *(ushort4*)(kf + dst) = make_ushort4(
          f2h(xk.x), f2h(xk.y), f2h(xk.z), f2h(xk.w));
    }
  } else {
    const int word = (b - 1024) * 4 + (tid >> 6);
    const int lane = tid & 63;
    const int row = word >> 5, wc = word & 31;
    int m = mask[(size_t)row * S_LEN + wc * 64 + lane];
    u64 bb = __ballot(m != 0);
    if (lane == 0) bits[word] = bb;
  }
}

// ---------------------------------------------------------------------------
// prep_w: il[k] = 1/sum(4 partials); wT[d][k] = fp16(il*V[k][d]) as SWIZZLED
// 64x64 tiles [bh][kc][ d*64 + (k ^ ((d&7)*8)) ]   (round-13 layout).
// ---------------------------------------------------------------------------
__global__ __launch_bounds__(256) void prep_w(
    const float* __restrict__ V, const float* __restrict__ part,
    u16* __restrict__ w_t) {
  __shared__ __align__(16) u16 ts[4096];
  const int tid = threadIdx.x;
  const int kc = blockIdx.x, bh = blockIdx.y;
  const int k = tid >> 2, dblk = (tid & 3) * 16;
  const size_t ko = (size_t)bh * S_LEN + kc * 64 + k;
  const float lsum = part[ko] + part[65536 + ko]
                   + part[131072 + ko] + part[196608 + ko];
  const float ilk = 1.0f / lsum;
  const float* vb = V + ko * 64 + dblk;
#pragma unroll
  for (int u = 0; u < 4; ++u) {
    float4 x = *(const float4*)(vb + u * 4);
    float xs[4] = {x.x, x.y, x.z, x.w};
#pragma unroll
    for (int e = 0; e < 4; ++e) {
      const int d = dblk + u * 4 + e;
      ts[d * 64 + (k ^ ((d & 7) << 3))] = f2h(xs[e] * ilk);
    }
  }
  __syncthreads();
  u16* dst = w_t + ((size_t)bh * NCH + kc) * 4096;
#pragma unroll
  for (int j = 0; j < 2; ++j)
    *(u16x8*)(dst + j * 2048 + tid * 8) = *(const u16x8*)(ts + j * 2048 + tid * 8);
}

// ---------------------------------------------------------------------------
// passA: partial column sums lp[k] = sum_{q in quarter} exp2(s~[q,k]).
// Grid (8 bx, 32 bh, 4 qp) x 512 -> 1024 blocks = 4 blocks/CU.
// launch_bounds(512,4): no spill. Single-barrier dbuf qbuf + setprio
// (round-15/16 version — measured best).
// ---------------------------------------------------------------------------
__global__ __launch_bounds__(512, 4) void passA(
    const u16* __restrict__ qf, const u16* __restrict__ kf,
    const u64* __restrict__ mbits, float* __restrict__ part) {
  __shared__ __align__(16) u16 qbuf[2][4096];  // 64 rows x 64 f16, swizzled

  const int tid = threadIdx.x;
  const int lane = tid & 63;
  const int w = tid >> 6;          // 0..7
  const int c = lane & 15;
  const int g = lane >> 4;
  const int bx = blockIdx.x;       // 0..7 (256 k each)
  const int bh = blockIdx.y;
  const int qp = blockIdx.z;       // 0..3 (512 q each)

  const size_t bh_off = (size_t)bh * S_LEN * 64;
  const int swc = (c & 7) << 3;

  // resident K A-frags (2 x 16-k tiles)
  f16x8 ka[2][2];
#pragma unroll
  for (int t = 0; t < 2; ++t) {
    const int row = bx * 256 + w * 32 + t * 16 + c;
#pragma unroll
    for (int h = 0; h < 2; ++h)
      ka[t][h] = *(const f16x8*)(kf + bh_off + (size_t)row * 64
                                 + ((h * 32 + g * 8) ^ swc));
  }

  // prologue: stage step 0 into buf 0
  u16x8 stg = *(const u16x8*)(qf + bh_off + (size_t)(qp * 512) * 64 + tid * 8);
  *(u16x8*)(&qbuf[0][0] + tid * 8) = stg;
  __syncthreads();

  float lp[2][4] = {{0.f, 0.f, 0.f, 0.f}, {0.f, 0.f, 0.f, 0.f}};
  const int word = bx * 4 + (w >> 1);
  const int sh0 = (w & 1) * 32;

  int cur = 0;
  for (int qs = 0; qs < 8; ++qs) {
    if (qs + 1 < 8)                        // T14: issue next step's loads now
      stg = *(const u16x8*)(qf + bh_off
            + (size_t)(qp * 512 + (qs + 1) * 64) * 64 + tid * 8);

    const u16* qb = &qbuf[cur][0];
#pragma unroll
    for (int sub = 0; sub < 4; ++sub) {
      f16x8 fh[2];
      const int rb = sub * 1024 + c * 64;
#pragma unroll
      for (int h = 0; h < 2; ++h)
        fh[h] = *(const f16x8*)(qb + rb + ((h * 32 + g * 8) ^ swc));
      const int qrow = qp * 512 + qs * 64 + sub * 16 + c;
      const u64 mw = mbits[(size_t)qrow * NCH + word];
#pragma unroll
      for (int t = 0; t < 2; ++t) {
        f32x4 acc = {0.f, 0.f, 0.f, 0.f};
        __builtin_amdgcn_s_setprio(1);
        acc = MFMAH(ka[t][0], fh[0], acc);  // IDENTICAL order in passC
        acc = MFMAH(ka[t][1], fh[1], acc);
        __builtin_amdgcn_s_setprio(0);
        const unsigned nib = (unsigned)(mw >> (sh0 + t * 16 + g * 4)) & 0xFu;
#pragma unroll
        for (int r = 0; r < 4; ++r) {
          const float tv = EXP2(acc[r]);    // select AFTER exp2 (same values)
          lp[t][r] += ((nib >> r) & 1) ? MASKED_P : tv;
        }
      }
    }

    // commit next step into the other buffer AFTER compute; single barrier
    if (qs + 1 < 8)
      *(u16x8*)(&qbuf[cur ^ 1][0] + tid * 8) = stg;
    __syncthreads();
    cur ^= 1;
  }

  // reduce over the 16 c-lanes of each g-group
#pragma unroll
  for (int off = 1; off < 16; off <<= 1)
#pragma unroll
    for (int t = 0; t < 2; ++t)
#pragma unroll
      for (int r = 0; r < 4; ++r) lp[t][r] += __shfl_xor(lp[t][r], off, 64);
  if (c == 0) {
#pragma unroll
    for (int t = 0; t < 2; ++t) {
      float4 o = {lp[t][0], lp[t][1], lp[t][2], lp[t][3]};
      *(float4*)(part + (size_t)qp * 65536 + (size_t)bh * S_LEN
                 + bx * 256 + w * 32 + t * 16 + g * 4) = o;
    }
  }
}

// ---------------------------------------------------------------------------
// passC: out[q,d] = sum_k exp2(s~[q,k]) * wT[d,k]   (all fp16 MFMA).
// ROUND-13 VERSION (measured best, 63.4us): dbuf staging, single barrier,
// p_s round-trip, full-rate MFMAH PV, no setprio.
// ---------------------------------------------------------------------------
__global__ __launch_bounds__(256, 4) void passC(
    const u16* __restrict__ qf, const u16* __restrict__ kf,
    const u16* __restrict__ w_t, const u64* __restrict__ mbits,
    float* __restrict__ out) {
  __shared__ __align__(16) u16 sbuf[2][8192]; // [buf][kf:4096 | wT:4096]
  __shared__ __align__(16) u16 p_s[4096];     // per-wave [16 q][64 k], swizzled

  const int tid = threadIdx.x;
  const int lane = tid & 63;
  const int w = tid >> 6;
  const int c = lane & 15;
  const int g = lane >> 4;
  const int qc = blockIdx.x;
  const int bh = blockIdx.y;

  const size_t bh_off = (size_t)bh * S_LEN * 64;
  const u16* tb_k = kf + bh_off;
  const u16* tb_w = w_t + (size_t)bh * NCH * 4096;
  const int swc = (c & 7) << 3;

  // Q B-frags from the swizzled plane (resident for the whole block)
  const int qrow = qc * 64 + w * 16 + c;
  f16x8 qb_[2];
#pragma unroll
  for (int h = 0; h < 2; ++h)
    qb_[h] = *(const f16x8*)(qf + bh_off + (size_t)qrow * 64
                             + ((h * 32 + g * 8) ^ swc));

  f32x4 oacc[4];
#pragma unroll
  for (int dt = 0; dt < 4; ++dt) oacc[dt] = (f32x4){0.f, 0.f, 0.f, 0.f};

  const int pbase = w * 1024 + c * 64;
  const int so = tid * 8;                     // staging offset (u16 units)

  // prologue: stage chunk 0 into buf 0
  u16x8 stg[4];
#pragma unroll
  for (int j = 0; j < 2; ++j) {
    stg[0 + j] = *(const u16x8*)(tb_k + j * 2048 + so);
    stg[2 + j] = *(const u16x8*)(tb_w + j * 2048 + so);
  }
#pragma unroll
  for (int j = 0; j < 2; ++j) {
    *(u16x8*)(&sbuf[0][0] + j * 2048 + so) = stg[0 + j];
    *(u16x8*)(&sbuf[0][0] + 4096 + j * 2048 + so) = stg[2 + j];
  }
  __syncthreads();

  int cur = 0;
  for (int kc = 0; kc < NCH; ++kc) {
    // T14: issue next chunk's global loads BEFORE compute
    if (kc + 1 < NCH) {
      const size_t nb = (size_t)(kc + 1) * 4096;
#pragma unroll
      for (int j = 0; j < 2; ++j) {
        stg[0 + j] = *(const u16x8*)(tb_k + nb + j * 2048 + so);
        stg[2 + j] = *(const u16x8*)(tb_w + nb + j * 2048 + so);
      }
    }

    const u16* bufc = &sbuf[cur][0];
    const u64 mw = mbits[(size_t)qrow * NCH + kc];

    // QK^T + mask + exp2 -> P (per-wave LDS tile; same-wave RAW only)
#pragma unroll
    for (int kt = 0; kt < 4; ++kt) {
      const int kbase = (16 * kt + c) * 64;
      f16x8 ak0 = *(const f16x8*)(bufc + kbase + ((g * 8) ^ swc));
      f16x8 ak1 = *(const f16x8*)(bufc + kbase + ((32 + g * 8) ^ swc));
      f32x4 acc = {0.f, 0.f, 0.f, 0.f};
      acc = MFMAH(ak0, qb_[0], acc);          // IDENTICAL order to passA
      acc = MFMAH(ak1, qb_[1], acc);
      const unsigned nib = (unsigned)(mw >> (kt * 16 + g * 4)) & 0xFu;
      u16 pb[4];
#pragma unroll
      for (int r = 0; r < 4; ++r) {
        const float tv = EXP2(acc[r]);        // select AFTER exp2
        pb[r] = f2h(((nib >> r) & 1) ? MASKED_P : tv);
      }
      *(ushort4*)(p_s + pbase + ((kt * 16 + g * 4) ^ swc)) =
          make_ushort4(pb[0], pb[1], pb[2], pb[3]);
    }

    // PV: oacc[dt] += wT[16dt.., k-slice] * P[k-slice, q]  (2 slices of 32)
#pragma unroll
    for (int s2 = 0; s2 < 2; ++s2) {
      const int koff = (s2 * 32 + g * 8) ^ swc;
      f16x8 pb8 = *(const f16x8*)(p_s + pbase + koff);
#pragma unroll
      for (int dt = 0; dt < 4; ++dt) {
        f16x8 av = *(const f16x8*)(bufc + 4096 + (16 * dt + c) * 64 + koff);
        oacc[dt] = MFMAH(av, pb8, oacc[dt]);
      }
    }

    // commit next chunk into the other buffer AFTER compute
    if (kc + 1 < NCH) {
      u16* bufn = &sbuf[cur ^ 1][0];
#pragma unroll
      for (int j = 0; j < 2; ++j) {
        *(u16x8*)(bufn + j * 2048 + so) = stg[0 + j];
        *(u16x8*)(bufn + 4096 + j * 2048 + so) = stg[2 + j];
      }
    }
    __syncthreads();          // single barrier per chunk
    cur ^= 1;
  }

  // epilogue: lane (c,g) owns row q = qrow, cols d = 16dt+4g+r
  float* ob = out + (bh_off + (size_t)qrow * 64);
#pragma unroll
  for (int dt = 0; dt < 4; ++dt) {
    float4 o = {oacc[dt][0], oacc[dt][1], oacc[dt][2], oacc[dt][3]};
    *(float4*)(ob + dt * 16 + g * 4) = o;
  }
}

// ===========================================================================
// FALLBACK (round-4 proven kernels) — used when ws_size is too small.
// ===========================================================================
__global__ __launch_bounds__(256) void passA_colsum(
    const float* __restrict__ Q, const float* __restrict__ K,
    const u64* __restrict__ mbits, float* __restrict__ il_out) {
  const int tid = threadIdx.x;
  const int lane = tid & 63;
  const int w = tid >> 6;
  const int c = lane & 15;
  const int g = lane >> 4;
  const int kc = blockIdx.x;
  const int bh = blockIdx.y;

  const float* Qb = Q + (size_t)bh * S_LEN * 64;
  const float* Kb = K + (size_t)bh * S_LEN * 64;

  bf16x8 kah[2], kal[2];
  {
    const int krow = kc * 64 + w * 16 + c;
#pragma unroll
    for (int h = 0; h < 2; ++h) {
      const float* src = Kb + (size_t)krow * 64 + h * 32 + g * 8;
      float4 x = *(const float4*)(src);
      float4 y = *(const float4*)(src + 4);
      float xs[8] = {x.x, x.y, x.z, x.w, y.x, y.y, y.z, y.w};
#pragma unroll
      for (int e = 0; e < 8; ++e) {
        u16 hh, ll; bfsplit(xs[e], hh, ll);
        kah[h][e] = (short)hh; kal[h][e] = (short)ll;
      }
    }
  }

  float lp[4] = {0.f, 0.f, 0.f, 0.f};
  const int shift = w * 16 + g * 4;

  for (int qs = 0; qs < S_LEN / 16; ++qs) {
    const int qrow = qs * 16 + c;
    bf16x8 qbh_[2], qbl_[2];
#pragma unroll
    for (int h = 0; h < 2; ++h) {
      const float* src = Qb + (size_t)qrow * 64 + h * 32 + g * 8;
      float4 x = *(const float4*)(src);
      float4 y = *(const float4*)(src + 4);
      float xs[8] = {x.x, x.y, x.z, x.w, y.x, y.y, y.z, y.w};
#pragma unroll
      for (int e = 0; e < 8; ++e) {
        u16 hh, ll; bfsplit(xs[e] * SC, hh, ll);
        qbh_[h][e] = (short)hh; qbl_[h][e] = (short)ll;
      }
    }
    f32x4 acc = {0.f, 0.f, 0.f, 0.f};
#pragma unroll
    for (int h = 0; h < 2; ++h) {
      acc = MFMA32(kah[h], qbh_[h], acc);
      acc = MFMA32(kal[h], qbh_[h], acc);
      acc = MFMA32(kah[h], qbl_[h], acc);
    }
    u64 mw = mbits[(size_t)qrow * NCH + kc];
    unsigned nib = (unsigned)(mw >> shift) & 0xFu;
#pragma unroll
    for (int r = 0; r < 4; ++r) {
      float s = ((nib >> r) & 1) ? -30.0f : acc[r];
      lp[r] += exp2f(s);
    }
  }
#pragma unroll
  for (int off = 1; off < 16; off <<= 1)
#pragma unroll
    for (int r = 0; r < 4; ++r) lp[r] += __shfl_xor(lp[r], off, 64);
  if (c == 0) {
    float4 o = {1.f / lp[0], 1.f / lp[1], 1.f / lp[2], 1.f / lp[3]};
    *(float4*)(il_out + (size_t)bh * S_LEN + kc * 64 + w * 16 + g * 4) = o;
  }
}

__global__ __launch_bounds__(256) void passC_out(
    const float* __restrict__ Q, const float* __restrict__ K,
    const float* __restrict__ V, const u64* __restrict__ mbits,
    const float* __restrict__ il_in, float* __restrict__ out) {
  __shared__ u16 kh_s[4096];
  __shared__ u16 kl_s[4096];
  __shared__ u16 vt_s[4096];
  __shared__ u16 p_s[4096];

  const int tid = threadIdx.x;
  const int lane = tid & 63;
  const int w = tid >> 6;
  const int c = lane & 15;
  const int g = lane >> 4;
  const int qc = blockIdx.x;
  const int bh = blockIdx.y;

  const float* Qb = Q + (size_t)bh * S_LEN * 64;
  const float* Kb = K + (size_t)bh * S_LEN * 64;
  const float* Vb = V + (size_t)bh * S_LEN * 64;

  bf16x8 qbh_[2], qbl_[2];
  {
    const int qrow = qc * 64 + w * 16 + c;
#pragma unroll
    for (int h = 0; h < 2; ++h) {
      const float* src = Qb + (size_t)qrow * 64 + h * 32 + g * 8;
      float4 x = *(const float4*)(src);
      float4 y = *(const float4*)(src + 4);
      float xs[8] = {x.x, x.y, x.z, x.w, y.x, y.y, y.z, y.w};
#pragma unroll
      for (int e = 0; e < 8; ++e) {
        u16 hh, ll; bfsplit(xs[e] * SC, hh, ll);
        qbh_[h][e] = (short)hh; qbl_[h][e] = (short)ll;
      }
    }
  }

  f32x4 oacc[4];
#pragma unroll
  for (int dt = 0; dt < 4; ++dt) oacc[dt] = (f32x4){0.f, 0.f, 0.f, 0.f};

  const int slot = tid & 15, r0 = tid >> 4;
  const int kv = tid & 63, dblk = tid >> 6;
  const int swc = (c & 7) << 3;
  const int pbase = w * 1024 + c * 64;

  for (int kc = 0; kc < NCH; ++kc) {
    __syncthreads();
#pragma unroll
    for (int p = 0; p < 4; ++p) {
      const int row = p * 16 + r0;
      float4 kx = *(const float4*)(Kb + (size_t)(kc * 64 + row) * 64 + slot * 4);
      float xs[4] = {kx.x, kx.y, kx.z, kx.w};
      u16 ha[4], la[4];
#pragma unroll
      for (int e = 0; e < 4; ++e) bfsplit(xs[e], ha[e], la[e]);
      const int idx = row * 64 + ((slot * 4) ^ ((row & 7) << 3));
      *(ushort4*)(kh_s + idx) = make_ushort4(ha[0], ha[1], ha[2], ha[3]);
      *(ushort4*)(kl_s + idx) = make_ushort4(la[0], la[1], la[2], la[3]);
    }
    {
      const float ilk = il_in[(size_t)bh * S_LEN + kc * 64 + kv];
#pragma unroll
      for (int u = 0; u < 4; ++u) {
        float4 vv = *(const float4*)(Vb + (size_t)(kc * 64 + kv) * 64 + dblk * 16 + u * 4);
        float xs[4] = {vv.x, vv.y, vv.z, vv.w};
#pragma unroll
        for (int e = 0; e < 4; ++e) {
          const int d = dblk * 16 + u * 4 + e;
          vt_s[d * 64 + (kv ^ ((d & 7) << 3))] = f2bf_rne(xs[e] * ilk);
        }
      }
    }
    __syncthreads();

    const u64 mw = mbits[(size_t)(qc * 64 + w * 16 + c) * NCH + kc];

#pragma unroll
    for (int kt = 0; kt < 4; ++kt) {
      const int kbase = (16 * kt + c) * 64;
      bf16x8 akh[2], akl[2];
#pragma unroll
      for (int h = 0; h < 2; ++h) {
        const int off = (h * 32 + g * 8) ^ swc;
        akh[h] = *(const bf16x8*)(kh_s + kbase + off);
        akl[h] = *(const bf16x8*)(kl_s + kbase + off);
      }
      f32x4 acc = {0.f, 0.f, 0.f, 0.f};
#pragma unroll
      for (int h = 0; h < 2; ++h) {
        acc = MFMA32(akh[h], qbh_[h], acc);
        acc = MFMA32(akl[h], qbh_[h], acc);
        acc = MFMA32(akh[h], qbl_[h], acc);
      }
      const unsigned nib = (unsigned)(mw >> (kt * 16 + g * 4)) & 0xFu;
      u16 pb[4];
#pragma unroll
      for (int r = 0; r < 4; ++r) {
        const float s = ((nib >> r) & 1) ? -30.0f : acc[r];
        pb[r] = f2bf_rne(exp2f(s));
      }
      *(ushort4*)(p_s + pbase + ((kt * 16 + g * 4) ^ swc)) =
          make_ushort4(pb[0], pb[1], pb[2], pb[3]);
    }
    __syncthreads();

#pragma unroll
    for (int s = 0; s < 2; ++s) {
      const int koff = (s * 32 + 8 * g) ^ swc;
      bf16x8 pb8 = *(const bf16x8*)(p_s + pbase + koff);
#pragma unroll
      for (int dt = 0; dt < 4; ++dt) {
        bf16x8 av = *(const bf16x8*)(vt_s + (16 * dt + c) * 64 + koff);
        oacc[dt] = MFMA32(av, pb8, oacc[dt]);
      }
    }
  }

  float* ob = out + ((size_t)bh * S_LEN + qc * 64 + w * 16 + c) * 64;
#pragma unroll
  for (int dt = 0; dt < 4; ++dt) {
    float4 o = {oacc[dt][0], oacc[dt][1], oacc[dt][2], oacc[dt][3]};
    *(float4*)(ob + dt * 16 + g * 4) = o;
  }
}

extern "C" void kernel_launch(void* const* d_in, const int* in_sizes, int n_in,
                              void* d_out, int out_size, void* d_ws, size_t ws_size,
                              hipStream_t stream) {
  (void)in_sizes; (void)n_in; (void)out_size;
  const float* q = (const float*)d_in[0];
  const float* k = (const float*)d_in[1];
  const float* v = (const float*)d_in[2];
  const int* mask = (const int*)d_in[3];
  float* out = (float*)d_out;

  // ws: mbits(512KB) | part[4][32][2048] f32 (1MB) | qf | kf | w_t
  // (fp16 planes, 8.4MB each)
  u64* mbits = (u64*)d_ws;
  float* part = (float*)((char*)d_ws + 524288);
  const size_t PL = (size_t)N_BH * S_LEN * 64;       // 4,194,304 elems/plane
  u16* qf = (u16*)((char*)d_ws + 524288 + 1048576);
  u16* kf = qf + PL;
  u16* w_t = kf + PL;
  const size_t need = 524288 + 1048576 + 3 * PL * sizeof(u16); // 26,738,688

  if (ws_size >= need) {
    prep_qk_mask<<<dim3(1024 + S_LEN * NCH / 4), 256, 0, stream>>>(
        q, k, mask, qf, kf, mbits);
    passA<<<dim3(8, N_BH, 4), 512, 0, stream>>>(qf, kf, mbits, part);
    prep_w<<<dim3(NCH, N_BH), 256, 0, stream>>>(v, part, w_t);
    passC<<<dim3(NCH, N_BH), 256, 0, stream>>>(qf, kf, w_t, mbits, out);
  } else {
    pack_mask<<<dim3(S_LEN * NCH / 4), 256, 0, stream>>>(mask, mbits);
    float* il = part;            // 256KB, fits
    dim3 grid(NCH, N_BH);
    passA_colsum<<<grid, 256, 0, stream>>>(q, k, mbits, il);
    passC_out<<<grid, 256, 0, stream>>>(q, k, v, mbits, il, out);
  }
}

// Round 18
// 124.265 us; speedup vs baseline: 1.0162x; 1.0162x over previous
//
#include <hip/hip_runtime.h>
#include <math.h>

// B=2, H=16, S=2048, DK=64
#define S_LEN 2048
#define NCH   32          // S/64 chunks
#define N_BH  32

typedef short bf16x8 __attribute__((ext_vector_type(8)));
typedef _Float16 f16x8 __attribute__((ext_vector_type(8)));
typedef _Float16 f16x4 __attribute__((ext_vector_type(4)));
typedef float f32x4  __attribute__((ext_vector_type(4)));
typedef unsigned short u16;
typedef unsigned short u16x8 __attribute__((ext_vector_type(8)));
typedef unsigned long long u64;

#define MFMA32(a,b,c) __builtin_amdgcn_mfma_f32_16x16x32_bf16((a),(b),(c),0,0,0)
#define MFMAH(a,b,c)  __builtin_amdgcn_mfma_f32_16x16x32_f16((a),(b),(c),0,0,0)
#define EXP2(x) __builtin_amdgcn_exp2f(x)

// 16x16x16 f16 MFMA with safe fallback (both branches correct).
__device__ __forceinline__ f32x4 mfma16(f16x4 a, f16x4 b, f32x4 c) {
#if __has_builtin(__builtin_amdgcn_mfma_f32_16x16x16f16)
  return __builtin_amdgcn_mfma_f32_16x16x16f16(a, b, c, 0, 0, 0);
#else
  const _Float16 z = (_Float16)0.0f;
  f16x8 a8 = {a[0], a[1], a[2], a[3], z, z, z, z};
  f16x8 b8 = {b[0], b[1], b[2], b[3], z, z, z, z};
  return MFMAH(a8, b8, c);
#endif
}

// (1/sqrt(64)) * log2(e): scores in log2 units; exp2 = one v_exp_f32.
#define SC        0.18033688011112042f
// masked P value = exp2(-14) EXACTLY (power of two, exact in f32 and f16).
// Fully-masked column degrades to EXACT uniform 1/2048.
#define MASKED_P  6.103515625e-05f

__device__ __forceinline__ u16 f2h(float x) {
  union { _Float16 h; u16 u; } v;
  v.h = (_Float16)x;          // RNE
  return v.u;
}
__device__ __forceinline__ u16 f2bf_rne(float x) {
  unsigned u = __float_as_uint(x);
  return (u16)((u + 0x7FFF + ((u >> 16) & 1)) >> 16);
}
__device__ __forceinline__ void bfsplit(float x, u16& h, u16& l) {
  unsigned u = __float_as_uint(x);
  h = (u16)(u >> 16);
  float hf = __uint_as_float(u & 0xFFFF0000u);
  l = f2bf_rne(x - hf);
}

// ---------------------------------------------------------------------------
// pack_mask (fallback path only).
// ---------------------------------------------------------------------------
__global__ __launch_bounds__(256) void pack_mask(
    const int* __restrict__ mask, u64* __restrict__ bits) {
  const int word = blockIdx.x * 4 + (threadIdx.x >> 6);
  const int lane = threadIdx.x & 63;
  const int row = word >> 5, wc = word & 31;
  int m = mask[(size_t)row * S_LEN + wc * 64 + lane];
  u64 b = __ballot(m != 0);
  if (lane == 0) bits[word] = b;
}

// ---------------------------------------------------------------------------
// prep_qk_mask: blocks <1024 convert Q*SC / K -> fp16 swizzled planes
// plane[row*64 + (col ^ ((row&7)*8))]; blocks >=1024 bit-pack the mask.
// ---------------------------------------------------------------------------
__global__ __launch_bounds__(256) void prep_qk_mask(
    const float* __restrict__ Q, const float* __restrict__ K,
    const int* __restrict__ mask,
    u16* __restrict__ qf, u16* __restrict__ kf, u64* __restrict__ bits) {
  const int b = blockIdx.x;
  const int tid = threadIdx.x;
  if (b < 1024) {
    const int slot = tid & 15, r0 = tid >> 4;
    const size_t rowbase = (size_t)b * 64;
#pragma unroll
    for (int p = 0; p < 4; ++p) {
      const size_t row = rowbase + p * 16 + r0;
      const size_t dst = row * 64 + ((slot * 4) ^ (((int)row & 7) << 3));
      float4 xq = *(const float4*)(Q + row * 64 + slot * 4);
      *(ushort4*)(qf + dst) = make_ushort4(
          f2h(xq.x * SC), f2h(xq.y * SC), f2h(xq.z * SC), f2h(xq.w * SC));
      float4 xk = *(const float4*)(K + row * 64 + slot * 4);
      *(ushort4*)(kf + dst) = make_ushort4(
          f2h(xk.x), f2h(xk.y), f2h(xk.z), f2h(xk.w));
    }
  } else {
    const int word = (b - 1024) * 4 + (tid >> 6);
    const int lane = tid & 63;
    const int row = word >> 5, wc = word & 31;
    int m = mask[(size_t)row * S_LEN + wc * 64 + lane];
    u64 bb = __ballot(m != 0);
    if (lane == 0) bits[word] = bb;
  }
}

// ---------------------------------------------------------------------------
// prep_w: il[k] = 1/sum(4 partials); wT = fp16(il*V) transposed, stored as
// kt-PAIRED b128 units so passC's PV A-frag read is one ds_read_b128:
//   for k = 16kt+4g+r:  col_u16 = ((2g + (kt>>1)) ^ (d&7))*8 + (kt&1)*4 + r
// ---------------------------------------------------------------------------
__global__ __launch_bounds__(256) void prep_w(
    const float* __restrict__ V, const float* __restrict__ part,
    u16* __restrict__ w_t) {
  __shared__ __align__(16) u16 ts[4096];
  const int tid = threadIdx.x;
  const int kc = blockIdx.x, bh = blockIdx.y;
  const int k = tid >> 2, dblk = (tid & 3) * 16;
  const int kt = k >> 4, gg = (k >> 2) & 3, r = k & 3;
  const int sub = (kt & 1) * 4 + r;
  const int lu = gg * 2 + (kt >> 1);        // logical 16B unit
  const size_t ko = (size_t)bh * S_LEN + kc * 64 + k;
  const float lsum = part[ko] + part[65536 + ko]
                   + part[131072 + ko] + part[196608 + ko];
  const float ilk = 1.0f / lsum;
  const float* vb = V + ko * 64 + dblk;
#pragma unroll
  for (int u = 0; u < 4; ++u) {
    float4 x = *(const float4*)(vb + u * 4);
    float xs[4] = {x.x, x.y, x.z, x.w};
#pragma unroll
    for (int e = 0; e < 4; ++e) {
      const int d = dblk + u * 4 + e;
      ts[d * 64 + (((lu ^ (d & 7)) << 3) + sub)] = f2h(xs[e] * ilk);
    }
  }
  __syncthreads();
  u16* dst = w_t + ((size_t)bh * NCH + kc) * 4096;
#pragma unroll
  for (int j = 0; j < 2; ++j)
    *(u16x8*)(dst + j * 2048 + tid * 8) = *(const u16x8*)(ts + j * 2048 + tid * 8);
}

// ---------------------------------------------------------------------------
// passA: partial column sums lp[k] = sum_{q in quarter} exp2(s~[q,k]).
// Grid (8 bx, 32 bh, 4 qp) x 512 -> 1024 blocks = 4 blocks/CU.
// launch_bounds(512,4): no spill. Single-barrier dbuf qbuf + setprio.
// ---------------------------------------------------------------------------
__global__ __launch_bounds__(512, 4) void passA(
    const u16* __restrict__ qf, const u16* __restrict__ kf,
    const u64* __restrict__ mbits, float* __restrict__ part) {
  __shared__ __align__(16) u16 qbuf[2][4096];  // 64 rows x 64 f16, swizzled

  const int tid = threadIdx.x;
  const int lane = tid & 63;
  const int w = tid >> 6;          // 0..7
  const int c = lane & 15;
  const int g = lane >> 4;
  const int bx = blockIdx.x;       // 0..7 (256 k each)
  const int bh = blockIdx.y;
  const int qp = blockIdx.z;       // 0..3 (512 q each)

  const size_t bh_off = (size_t)bh * S_LEN * 64;
  const int swc = (c & 7) << 3;

  // resident K A-frags (2 x 16-k tiles)
  f16x8 ka[2][2];
#pragma unroll
  for (int t = 0; t < 2; ++t) {
    const int row = bx * 256 + w * 32 + t * 16 + c;
#pragma unroll
    for (int h = 0; h < 2; ++h)
      ka[t][h] = *(const f16x8*)(kf + bh_off + (size_t)row * 64
                                 + ((h * 32 + g * 8) ^ swc));
  }

  // prologue: stage step 0 into buf 0
  u16x8 stg = *(const u16x8*)(qf + bh_off + (size_t)(qp * 512) * 64 + tid * 8);
  *(u16x8*)(&qbuf[0][0] + tid * 8) = stg;
  __syncthreads();

  float lp[2][4] = {{0.f, 0.f, 0.f, 0.f}, {0.f, 0.f, 0.f, 0.f}};
  const int word = bx * 4 + (w >> 1);
  const int sh0 = (w & 1) * 32;

  int cur = 0;
  for (int qs = 0; qs < 8; ++qs) {
    if (qs + 1 < 8)                        // T14: issue next step's loads now
      stg = *(const u16x8*)(qf + bh_off
            + (size_t)(qp * 512 + (qs + 1) * 64) * 64 + tid * 8);

    const u16* qb = &qbuf[cur][0];
#pragma unroll
    for (int sub = 0; sub < 4; ++sub) {
      f16x8 fh[2];
      const int rb = sub * 1024 + c * 64;
#pragma unroll
      for (int h = 0; h < 2; ++h)
        fh[h] = *(const f16x8*)(qb + rb + ((h * 32 + g * 8) ^ swc));
      const int qrow = qp * 512 + qs * 64 + sub * 16 + c;
      const u64 mw = mbits[(size_t)qrow * NCH + word];
#pragma unroll
      for (int t = 0; t < 2; ++t) {
        f32x4 acc = {0.f, 0.f, 0.f, 0.f};
        __builtin_amdgcn_s_setprio(1);
        acc = MFMAH(ka[t][0], fh[0], acc);  // IDENTICAL order in passC
        acc = MFMAH(ka[t][1], fh[1], acc);
        __builtin_amdgcn_s_setprio(0);
        const unsigned nib = (unsigned)(mw >> (sh0 + t * 16 + g * 4)) & 0xFu;
#pragma unroll
        for (int r = 0; r < 4; ++r) {
          const float tv = EXP2(acc[r]);    // select AFTER exp2 (same values)
          lp[t][r] += ((nib >> r) & 1) ? MASKED_P : tv;
        }
      }
    }

    // commit next step into the other buffer AFTER compute; single barrier
    if (qs + 1 < 8)
      *(u16x8*)(&qbuf[cur ^ 1][0] + tid * 8) = stg;
    __syncthreads();
    cur ^= 1;
  }

  // reduce over the 16 c-lanes of each g-group
#pragma unroll
  for (int off = 1; off < 16; off <<= 1)
#pragma unroll
    for (int t = 0; t < 2; ++t)
#pragma unroll
      for (int r = 0; r < 4; ++r) lp[t][r] += __shfl_xor(lp[t][r], off, 64);
  if (c == 0) {
#pragma unroll
    for (int t = 0; t < 2; ++t) {
      float4 o = {lp[t][0], lp[t][1], lp[t][2], lp[t][3]};
      *(float4*)(part + (size_t)qp * 65536 + (size_t)bh * S_LEN
                 + bx * 256 + w * 32 + t * 16 + g * 4) = o;
    }
  }
}

// ---------------------------------------------------------------------------
// passC: out[q,d] = sum_k exp2(s~[q,k]) * wT[d,k].
// Dbuf staging (single barrier), P IN REGISTERS (swapped-QK output ==
// 16x16x16 B-frag), W A-frags via kt-paired b128. LDS 32KB -> 4 blocks/CU.
// (Round-16 version — best measured total, 124.45us.)
// ---------------------------------------------------------------------------
__global__ __launch_bounds__(256, 4) void passC(
    const u16* __restrict__ qf, const u16* __restrict__ kf,
    const u16* __restrict__ w_t, const u64* __restrict__ mbits,
    float* __restrict__ out) {
  __shared__ __align__(16) u16 sbuf[2][8192]; // [buf][kf:4096 | wT:4096]

  const int tid = threadIdx.x;
  const int lane = tid & 63;
  const int w = tid >> 6;
  const int c = lane & 15;
  const int g = lane >> 4;
  const int qc = blockIdx.x;
  const int bh = blockIdx.y;

  const size_t bh_off = (size_t)bh * S_LEN * 64;
  const u16* tb_k = kf + bh_off;
  const u16* tb_w = w_t + (size_t)bh * NCH * 4096;
  const int swc = (c & 7) << 3;

  // Q B-frags from the swizzled plane (resident for the whole block)
  const int qrow = qc * 64 + w * 16 + c;
  f16x8 qb_[2];
#pragma unroll
  for (int h = 0; h < 2; ++h)
    qb_[h] = *(const f16x8*)(qf + bh_off + (size_t)qrow * 64
                             + ((h * 32 + g * 8) ^ swc));

  f32x4 oacc[4];
#pragma unroll
  for (int dt = 0; dt < 4; ++dt) oacc[dt] = (f32x4){0.f, 0.f, 0.f, 0.f};

  const int so = tid * 8;                     // staging offset (u16 units)

  // prologue: stage chunk 0 into buf 0
  u16x8 stg[4];
#pragma unroll
  for (int j = 0; j < 2; ++j) {
    stg[0 + j] = *(const u16x8*)(tb_k + j * 2048 + so);
    stg[2 + j] = *(const u16x8*)(tb_w + j * 2048 + so);
  }
#pragma unroll
  for (int j = 0; j < 2; ++j) {
    *(u16x8*)(&sbuf[0][0] + j * 2048 + so) = stg[0 + j];
    *(u16x8*)(&sbuf[0][0] + 4096 + j * 2048 + so) = stg[2 + j];
  }
  __syncthreads();

  int cur = 0;
  for (int kc = 0; kc < NCH; ++kc) {
    // T14: issue next chunk's global loads BEFORE compute
    if (kc + 1 < NCH) {
      const size_t nb = (size_t)(kc + 1) * 4096;
#pragma unroll
      for (int j = 0; j < 2; ++j) {
        stg[0 + j] = *(const u16x8*)(tb_k + nb + j * 2048 + so);
        stg[2 + j] = *(const u16x8*)(tb_w + nb + j * 2048 + so);
      }
    }

    const u16* bufc = &sbuf[cur][0];
    const u64 mw = mbits[(size_t)qrow * NCH + kc];

    // QK^T + mask + exp2 -> P in registers (pf[kt], const-indexed)
    f16x4 pf[4];
#pragma unroll
    for (int kt = 0; kt < 4; ++kt) {
      const int kbase = (16 * kt + c) * 64;
      f16x8 ak0 = *(const f16x8*)(bufc + kbase + ((g * 8) ^ swc));
      f16x8 ak1 = *(const f16x8*)(bufc + kbase + ((32 + g * 8) ^ swc));
      f32x4 acc = {0.f, 0.f, 0.f, 0.f};
      acc = MFMAH(ak0, qb_[0], acc);          // IDENTICAL order to passA
      acc = MFMAH(ak1, qb_[1], acc);
      const unsigned nib = (unsigned)(mw >> (kt * 16 + g * 4)) & 0xFu;
#pragma unroll
      for (int r = 0; r < 4; ++r) {
        const float tv = EXP2(acc[r]);        // select AFTER exp2
        pf[kt][r] = (_Float16)(((nib >> r) & 1) ? MASKED_P : tv);
      }
    }

    // PV: one b128 read per (ktp, dt) yields BOTH kt A-frags of the pair.
#pragma unroll
    for (int ktp = 0; ktp < 2; ++ktp) {
#pragma unroll
      for (int dt = 0; dt < 4; ++dt) {
        const int aoff = 4096 + (16 * dt + c) * 64
                       + (((g * 2 + ktp) ^ (c & 7)) << 3);
        f16x8 av = *(const f16x8*)(bufc + aoff);
        f16x4 alo = {av[0], av[1], av[2], av[3]};   // kt = 2*ktp
        f16x4 ahi = {av[4], av[5], av[6], av[7]};   // kt = 2*ktp+1
        oacc[dt] = mfma16(alo, pf[ktp * 2], oacc[dt]);
        oacc[dt] = mfma16(ahi, pf[ktp * 2 + 1], oacc[dt]);
      }
    }

    // commit next chunk into the other buffer AFTER compute
    if (kc + 1 < NCH) {
      u16* bufn = &sbuf[cur ^ 1][0];
#pragma unroll
      for (int j = 0; j < 2; ++j) {
        *(u16x8*)(bufn + j * 2048 + so) = stg[0 + j];
        *(u16x8*)(bufn + 4096 + j * 2048 + so) = stg[2 + j];
      }
    }
    __syncthreads();          // single barrier per chunk
    cur ^= 1;
  }

  // epilogue: lane (c,g) owns row q = qrow, cols d = 16dt+4g+r
  float* ob = out + (bh_off + (size_t)qrow * 64);
#pragma unroll
  for (int dt = 0; dt < 4; ++dt) {
    float4 o = {oacc[dt][0], oacc[dt][1], oacc[dt][2], oacc[dt][3]};
    *(float4*)(ob + dt * 16 + g * 4) = o;
  }
}

// ===========================================================================
// FALLBACK (round-4 proven kernels) — used when ws_size is too small.
// ===========================================================================
__global__ __launch_bounds__(256) void passA_colsum(
    const float* __restrict__ Q, const float* __restrict__ K,
    const u64* __restrict__ mbits, float* __restrict__ il_out) {
  const int tid = threadIdx.x;
  const int lane = tid & 63;
  const int w = tid >> 6;
  const int c = lane & 15;
  const int g = lane >> 4;
  const int kc = blockIdx.x;
  const int bh = blockIdx.y;

  const float* Qb = Q + (size_t)bh * S_LEN * 64;
  const float* Kb = K + (size_t)bh * S_LEN * 64;

  bf16x8 kah[2], kal[2];
  {
    const int krow = kc * 64 + w * 16 + c;
#pragma unroll
    for (int h = 0; h < 2; ++h) {
      const float* src = Kb + (size_t)krow * 64 + h * 32 + g * 8;
      float4 x = *(const float4*)(src);
      float4 y = *(const float4*)(src + 4);
      float xs[8] = {x.x, x.y, x.z, x.w, y.x, y.y, y.z, y.w};
#pragma unroll
      for (int e = 0; e < 8; ++e) {
        u16 hh, ll; bfsplit(xs[e], hh, ll);
        kah[h][e] = (short)hh; kal[h][e] = (short)ll;
      }
    }
  }

  float lp[4] = {0.f, 0.f, 0.f, 0.f};
  const int shift = w * 16 + g * 4;

  for (int qs = 0; qs < S_LEN / 16; ++qs) {
    const int qrow = qs * 16 + c;
    bf16x8 qbh_[2], qbl_[2];
#pragma unroll
    for (int h = 0; h < 2; ++h) {
      const float* src = Qb + (size_t)qrow * 64 + h * 32 + g * 8;
      float4 x = *(const float4*)(src);
      float4 y = *(const float4*)(src + 4);
      float xs[8] = {x.x, x.y, x.z, x.w, y.x, y.y, y.z, y.w};
#pragma unroll
      for (int e = 0; e < 8; ++e) {
        u16 hh, ll; bfsplit(xs[e] * SC, hh, ll);
        qbh_[h][e] = (short)hh; qbl_[h][e] = (short)ll;
      }
    }
    f32x4 acc = {0.f, 0.f, 0.f, 0.f};
#pragma unroll
    for (int h = 0; h < 2; ++h) {
      acc = MFMA32(kah[h], qbh_[h], acc);
      acc = MFMA32(kal[h], qbh_[h], acc);
      acc = MFMA32(kah[h], qbl_[h], acc);
    }
    u64 mw = mbits[(size_t)qrow * NCH + kc];
    unsigned nib = (unsigned)(mw >> shift) & 0xFu;
#pragma unroll
    for (int r = 0; r < 4; ++r) {
      float s = ((nib >> r) & 1) ? -30.0f : acc[r];
      lp[r] += exp2f(s);
    }
  }
#pragma unroll
  for (int off = 1; off < 16; off <<= 1)
#pragma unroll
    for (int r = 0; r < 4; ++r) lp[r] += __shfl_xor(lp[r], off, 64);
  if (c == 0) {
    float4 o = {1.f / lp[0], 1.f / lp[1], 1.f / lp[2], 1.f / lp[3]};
    *(float4*)(il_out + (size_t)bh * S_LEN + kc * 64 + w * 16 + g * 4) = o;
  }
}

__global__ __launch_bounds__(256) void passC_out(
    const float* __restrict__ Q, const float* __restrict__ K,
    const float* __restrict__ V, const u64* __restrict__ mbits,
    const float* __restrict__ il_in, float* __restrict__ out) {
  __shared__ u16 kh_s[4096];
  __shared__ u16 kl_s[4096];
  __shared__ u16 vt_s[4096];
  __shared__ u16 p_s[4096];

  const int tid = threadIdx.x;
  const int lane = tid & 63;
  const int w = tid >> 6;
  const int c = lane & 15;
  const int g = lane >> 4;
  const int qc = blockIdx.x;
  const int bh = blockIdx.y;

  const float* Qb = Q + (size_t)bh * S_LEN * 64;
  const float* Kb = K + (size_t)bh * S_LEN * 64;
  const float* Vb = V + (size_t)bh * S_LEN * 64;

  bf16x8 qbh_[2], qbl_[2];
  {
    const int qrow = qc * 64 + w * 16 + c;
#pragma unroll
    for (int h = 0; h < 2; ++h) {
      const float* src = Qb + (size_t)qrow * 64 + h * 32 + g * 8;
      float4 x = *(const float4*)(src);
      float4 y = *(const float4*)(src + 4);
      float xs[8] = {x.x, x.y, x.z, x.w, y.x, y.y, y.z, y.w};
#pragma unroll
      for (int e = 0; e < 8; ++e) {
        u16 hh, ll; bfsplit(xs[e] * SC, hh, ll);
        qbh_[h][e] = (short)hh; qbl_[h][e] = (short)ll;
      }
    }
  }

  f32x4 oacc[4];
#pragma unroll
  for (int dt = 0; dt < 4; ++dt) oacc[dt] = (f32x4){0.f, 0.f, 0.f, 0.f};

  const int slot = tid & 15, r0 = tid >> 4;
  const int kv = tid & 63, dblk = tid >> 6;
  const int swc = (c & 7) << 3;
  const int pbase = w * 1024 + c * 64;

  for (int kc = 0; kc < NCH; ++kc) {
    __syncthreads();
#pragma unroll
    for (int p = 0; p < 4; ++p) {
      const int row = p * 16 + r0;
      float4 kx = *(const float4*)(Kb + (size_t)(kc * 64 + row) * 64 + slot * 4);
      float xs[4] = {kx.x, kx.y, kx.z, kx.w};
      u16 ha[4], la[4];
#pragma unroll
      for (int e = 0; e < 4; ++e) bfsplit(xs[e], ha[e], la[e]);
      const int idx = row * 64 + ((slot * 4) ^ ((row & 7) << 3));
      *(ushort4*)(kh_s + idx) = make_ushort4(ha[0], ha[1], ha[2], ha[3]);
      *(ushort4*)(kl_s + idx) = make_ushort4(la[0], la[1], la[2], la[3]);
    }
    {
      const float ilk = il_in[(size_t)bh * S_LEN + kc * 64 + kv];
#pragma unroll
      for (int u = 0; u < 4; ++u) {
        float4 vv = *(const float4*)(Vb + (size_t)(kc * 64 + kv) * 64 + dblk * 16 + u * 4);
        float xs[4] = {vv.x, vv.y, vv.z, vv.w};
#pragma unroll
        for (int e = 0; e < 4; ++e) {
          const int d = dblk * 16 + u * 4 + e;
          vt_s[d * 64 + (kv ^ ((d & 7) << 3))] = f2bf_rne(xs[e] * ilk);
        }
      }
    }
    __syncthreads();

    const u64 mw = mbits[(size_t)(qc * 64 + w * 16 + c) * NCH + kc];

#pragma unroll
    for (int kt = 0; kt < 4; ++kt) {
      const int kbase = (16 * kt + c) * 64;
      bf16x8 akh[2], akl[2];
#pragma unroll
      for (int h = 0; h < 2; ++h) {
        const int off = (h * 32 + g * 8) ^ swc;
        akh[h] = *(const bf16x8*)(kh_s + kbase + off);
        akl[h] = *(const bf16x8*)(kl_s + kbase + off);
      }
      f32x4 acc = {0.f, 0.f, 0.f, 0.f};
#pragma unroll
      for (int h = 0; h < 2; ++h) {
        acc = MFMA32(akh[h], qbh_[h], acc);
        acc = MFMA32(akl[h], qbh_[h], acc);
        acc = MFMA32(akh[h], qbl_[h], acc);
      }
      const unsigned nib = (unsigned)(mw >> (kt * 16 + g * 4)) & 0xFu;
      u16 pb[4];
#pragma unroll
      for (int r = 0; r < 4; ++r) {
        const float s = ((nib >> r) & 1) ? -30.0f : acc[r];
        pb[r] = f2bf_rne(exp2f(s));
      }
      *(ushort4*)(p_s + pbase + ((kt * 16 + g * 4) ^ swc)) =
          make_ushort4(pb[0], pb[1], pb[2], pb[3]);
    }
    __syncthreads();

#pragma unroll
    for (int s = 0; s < 2; ++s) {
      const int koff = (s * 32 + 8 * g) ^ swc;
      bf16x8 pb8 = *(const bf16x8*)(p_s + pbase + koff);
#pragma unroll
      for (int dt = 0; dt < 4; ++dt) {
        bf16x8 av = *(const bf16x8*)(vt_s + (16 * dt + c) * 64 + koff);
        oacc[dt] = MFMA32(av, pb8, oacc[dt]);
      }
    }
  }

  float* ob = out + ((size_t)bh * S_LEN + qc * 64 + w * 16 + c) * 64;
#pragma unroll
  for (int dt = 0; dt < 4; ++dt) {
    float4 o = {oacc[dt][0], oacc[dt][1], oacc[dt][2], oacc[dt][3]};
    *(float4*)(ob + dt * 16 + g * 4) = o;
  }
}

extern "C" void kernel_launch(void* const* d_in, const int* in_sizes, int n_in,
                              void* d_out, int out_size, void* d_ws, size_t ws_size,
                              hipStream_t stream) {
  (void)in_sizes; (void)n_in; (void)out_size;
  const float* q = (const float*)d_in[0];
  const float* k = (const float*)d_in[1];
  const float* v = (const float*)d_in[2];
  const int* mask = (const int*)d_in[3];
  float* out = (float*)d_out;

  // ws: mbits(512KB) | part[4][32][2048] f32 (1MB) | qf | kf | w_t
  // (fp16 planes, 8.4MB each)
  u64* mbits = (u64*)d_ws;
  float* part = (float*)((char*)d_ws + 524288);
  const size_t PL = (size_t)N_BH * S_LEN * 64;       // 4,194,304 elems/plane
  u16* qf = (u16*)((char*)d_ws + 524288 + 1048576);
  u16* kf = qf + PL;
  u16* w_t = kf + PL;
  const size_t need = 524288 + 1048576 + 3 * PL * sizeof(u16); // 26,738,688

  if (ws_size >= need) {
    prep_qk_mask<<<dim3(1024 + S_LEN * NCH / 4), 256, 0, stream>>>(
        q, k, mask, qf, kf, mbits);
    passA<<<dim3(8, N_BH, 4), 512, 0, stream>>>(qf, kf, mbits, part);
    prep_w<<<dim3(NCH, N_BH), 256, 0, stream>>>(v, part, w_t);
    passC<<<dim3(NCH, N_BH), 256, 0, stream>>>(qf, kf, w_t, mbits, out);
  } else {
    pack_mask<<<dim3(S_LEN * NCH / 4), 256, 0, stream>>>(mask, mbits);
    float* il = part;            // 256KB, fits
    dim3 grid(NCH, N_BH);
    passA_colsum<<<grid, 256, 0, stream>>>(q, k, mbits, il);
    passC_out<<<grid, 256, 0, stream>>>(q, k, v, mbits, il, out);
  }
}